// Round 12
// baseline (42924.054 us; speedup 1.0000x reference)
//
#include <hip/hip_runtime.h>
#include <math.h>
#include <stdint.h>

// ---------------------------------------------------------------------------
// DualSpectralDiffusion: faithful replication of the JAX reference.
//  - f64 LAPACK-style eigh: sytd2 as 510 per-column kernel launches (the
//    launch boundary is the grid barrier - no software sync), 8 matrices
//    batched; D&C w/ slaed2 deflation mimicry, sign-faithful vs ssyevd
//  - exact threefry2x32 / jax.random replication (PARTITIONABLE stream)
//  - f32 diffusion loop, noise threefry fused into the update-GEMM epilogue
// ---------------------------------------------------------------------------

#define NT 256
#define SZF 131072          // 512*256 floats per (b) tensor
#define MATSZ 262144        // 512*512

// ws layout (bytes):
//   V (f64, 8 slots)      [0, 16MB)   -- Vt32 overlays: pass0 [0,4MB), pass1 [8,12MB)
//   A8 (f64, 8 slots)     [16,32MB)   -- dead after sytd2; D&C overlays:
//                                        A64dc [16,24), Zb [24,32), Sm [32,40)
//   smalls (f64)          [40MB, ~42.3MB)
//   eig32                 [42.5MB, +16KB)
//   diffusion overlay: cond@16MB, E@18, xall@22, xspec@26, hbuf@30
// smalls (double idx): d[sg*512], e@4096, tau@8192, org@12288,
//   rot@12544+(sg*32+m)*1024 (ends 274688), acc pp@274688(+4096),
//   col pp@282880(+4096), vv pp@291072(+4096) -> ends 299264

// ----------------------------- threefry ------------------------------------
__host__ __device__ static inline unsigned rotl32(unsigned v, int r){ return (v<<r)|(v>>(32-r)); }

__host__ __device__ static inline void tf2x32(unsigned k0, unsigned k1,
                                              unsigned x0, unsigned x1,
                                              unsigned* o0, unsigned* o1){
  unsigned ks2 = k0 ^ k1 ^ 0x1BD11BDAu;
  x0 += k0; x1 += k1;
#define TF4(r0,r1,r2,r3) \
  x0 += x1; x1 = rotl32(x1,r0); x1 ^= x0; \
  x0 += x1; x1 = rotl32(x1,r1); x1 ^= x0; \
  x0 += x1; x1 = rotl32(x1,r2); x1 ^= x0; \
  x0 += x1; x1 = rotl32(x1,r3); x1 ^= x0;
  TF4(13,15,26,6)  x0 += k1;  x1 += ks2 + 1u;
  TF4(17,29,16,24) x0 += ks2; x1 += k0 + 2u;
  TF4(13,15,26,6)  x0 += k0;  x1 += k1 + 3u;
  TF4(17,29,16,24) x0 += k1;  x1 += ks2 + 4u;
  TF4(13,15,26,6)  x0 += ks2; x1 += k0 + 5u;
#undef TF4
  *o0 = x0; *o1 = x1;
}

// XLA ErfInv f32 polynomial; matches lax.erf_inv expansion.
__device__ static inline float erfinv_xla(float x){
  float w = -log1pf(-x*x);
  float p;
  if (w < 5.0f){
    w -= 2.5f;
    p = 2.81022636e-08f;
    p = fmaf(p, w, 3.43273939e-07f);
    p = fmaf(p, w, -3.5233877e-06f);
    p = fmaf(p, w, -4.39150654e-06f);
    p = fmaf(p, w, 0.00021858087f);
    p = fmaf(p, w, -0.00125372503f);
    p = fmaf(p, w, -0.00417768164f);
    p = fmaf(p, w, 0.246640727f);
    p = fmaf(p, w, 1.50140941f);
  } else {
    w = sqrtf(w) - 3.0f;
    p = -0.000200214257f;
    p = fmaf(p, w, 0.000100950558f);
    p = fmaf(p, w, 0.00134934322f);
    p = fmaf(p, w, -0.00367342844f);
    p = fmaf(p, w, 0.00573950773f);
    p = fmaf(p, w, -0.0076224613f);
    p = fmaf(p, w, 0.00943887047f);
    p = fmaf(p, w, 1.00167406f);
    p = fmaf(p, w, 2.83297682f);
  }
  return p*x;
}

__device__ static inline float bits_to_normal(unsigned bits){
  const float MINV = -0.99999994f;   // nextafter(-1,0) in f32
  float f = __uint_as_float((bits >> 9) | 0x3f800000u) - 1.0f;
  float u = fmaxf(MINV, fmaf(f, 2.0f, MINV));
  return 1.41421356237309515f * erfinv_xla(u);
}

// ------------------------------- eigh: sytd2 -------------------------------
__global__ void k_prep8(double* A8, const float* Gs, const float* Gt){
  size_t i = (size_t)blockIdx.x*256 + threadIdx.x;   // < 2097152
  A8[i] = (double)((i < 4u*MATSZ) ? Gs[i] : Gt[i - 4u*MATSZ]);
}

// reflector 0 per matrix (one block per matrix)
__global__ __launch_bounds__(256) void k_sy_init_a(const float* Gs, const float* Gt,
                                                   double* Vb, double* smalls){
  int sg = blockIdx.x, t = threadIdx.x, wave = t>>6, lane = t&63;
  const float* G = (sg < 4) ? (Gs + (size_t)sg*MATSZ) : (Gt + (size_t)(sg-4)*MATSZ);
  double* V  = Vb + (size_t)sg*MATSZ;
  double* e  = smalls + 4096 + (size_t)sg*512;
  double* tu = smalls + 8192 + (size_t)sg*512;
  double* vv0  = smalls + 291072 + (size_t)sg*512;
  double* col0 = smalls + 282880 + (size_t)sg*512;
  __shared__ double col2[512];
  __shared__ double red[4];
  __shared__ double bc[2];
  for (int r=t; r<512; r+=256) col2[r] = (r>=1) ? (double)G[(size_t)r*512] : 0.0;
  __syncthreads();
  double part = 0.0;
  for (int r=2+t; r<512; r+=256) part += col2[r]*col2[r];
  #pragma unroll
  for (int off=32; off; off>>=1) part += __shfl_down(part, off, 64);
  if (lane==0) red[wave]=part;
  __syncthreads();
  if (t==0){
    double xsq = red[0]+red[1]+red[2]+red[3];
    double alpha = col2[1];
    double beta,tv,scal;
    if (xsq == 0.0){ beta=alpha; tv=0.0; scal=0.0; }
    else {
      beta = -copysign(sqrt(alpha*alpha + xsq), alpha);   // LAPACK slarfg
      tv = (beta - alpha)/beta;
      scal = 1.0/(alpha - beta);
    }
    e[0]=beta; tu[0]=tv; bc[0]=tv; bc[1]=scal;
  }
  __syncthreads();
  double tauv = bc[0], scal = bc[1];
  for (int r=t; r<512; r+=256){
    double v = 0.0;
    if (r==1) v = 1.0;
    else if (r>1) v = (tauv==0.0) ? 0.0 : col2[r]*scal;
    vv0[r] = v;
    if (r>=1) V[r] = v;
  }
  for (int r=1+t; r<512; r+=256) col0[r] = (double)G[(size_t)r*512 + 1];
}

// initial matvec acc0 = A*v0 on owned rows (16 blocks/matrix, rows r%16==g)
__global__ __launch_bounds__(256) void k_sy_init_b(const double* A8, double* smalls){
  int sg = blockIdx.x >> 4, g = blockIdx.x & 15;
  int t = threadIdx.x, wave = t>>6, lane = t&63;
  const double* A = A8 + (size_t)sg*MATSZ;
  const double* vv0 = smalls + 291072 + (size_t)sg*512;
  double* acc0 = smalls + 274688 + (size_t)sg*512;
  __shared__ double vv[512];
  for (int r=t; r<512; r+=256) vv[r] = vv0[r];
  __syncthreads();
  int r0 = 1 + ((g - 1) & 15);
  for (int r = r0 + 16*wave; r < 512; r += 64){
    const double* Ar = A + (size_t)r*512;
    double p = 0.0;
    for (int c=lane; c<512; c+=64) p += Ar[c]*vv[c];
    #pragma unroll
    for (int off=32; off; off>>=1) p += __shfl_down(p, off, 64);
    if (lane==0) acc0[r] = p;
  }
}

// one Householder column for all 8 matrices; launch boundary = barrier.
// Arithmetic operand-identical to the verified r11 iteration body.
__global__ __launch_bounds__(256) void k_sy_step(double* A8, double* Vb,
                                                 double* smalls, int i){
  int sg = blockIdx.x >> 4, g = blockIdx.x & 15;
  double* A = A8 + (size_t)sg*MATSZ;
  double* V = Vb + (size_t)sg*MATSZ;
  double* e  = smalls + 4096 + (size_t)sg*512;
  double* tu = smalls + 8192 + (size_t)sg*512;
  double* accB = smalls + 274688 + (size_t)sg*512;
  double* colB = smalls + 282880 + (size_t)sg*512;
  double* vvB  = smalls + 291072 + (size_t)sg*512;
  double* accR = (i&1) ? accB+4096 : accB;
  double* accW = (i&1) ? accB : accB+4096;
  double* colR = (i&1) ? colB+4096 : colB;
  double* colW = (i&1) ? colB : colB+4096;
  const double* vvR = (i&1) ? vvB+4096 : vvB;
  double* vvW = (i&1) ? vvB : vvB+4096;
  int t = threadIdx.x, wave = t>>6, lane = t&63;
  int lo = i+1, lo2 = i+2;
  __shared__ double vv[512], wv[512], col2[512], acc[512];
  __shared__ double red[4];
  __shared__ double bc[4];
  double tauv = tu[i];
  // pass1: load state + dot partial
  double part = 0.0;
  for (int r=lo+t; r<512; r+=256){
    double a_ = accR[r], c_ = colR[r], v_ = vvR[r];
    acc[r]=a_; col2[r]=c_; vv[r]=v_;
    part += (tauv*a_)*v_;
  }
  #pragma unroll
  for (int off=32; off; off>>=1) part += __shfl_down(part, off, 64);
  if (lane==0) red[wave]=part;
  __syncthreads();
  if (t==0){ double dot=red[0]+red[1]+red[2]+red[3]; bc[2] = -0.5*tauv*dot; }
  __syncthreads();
  // pass2: w = tau*acc + alpha2*v ; col2 -= v*wlo + w*vlo
  {
    double alpha2 = bc[2];
    double vlo = vv[lo];
    double wlo = fma(alpha2, vlo, tauv*acc[lo]);
    for (int r=lo+t; r<512; r+=256){
      double wr = fma(alpha2, vv[r], tauv*acc[r]);
      wv[r]=wr;
      col2[r] = col2[r] - vv[r]*wlo - wr*vlo;
    }
  }
  __syncthreads();
  // xsq over r>=lo2+1
  part = 0.0;
  for (int r=lo2+1+t; r<512; r+=256) part += col2[r]*col2[r];
  #pragma unroll
  for (int off=32; off; off>>=1) part += __shfl_down(part, off, 64);
  if (lane==0) red[wave]=part;
  __syncthreads();
  if (t==0){
    double xsq = red[0]+red[1]+red[2]+red[3];
    double alpha = col2[lo2];
    double beta,tau2,scal2;
    if (xsq == 0.0){ beta=alpha; tau2=0.0; scal2=0.0; }
    else {
      beta = -copysign(sqrt(alpha*alpha + xsq), alpha);
      tau2 = (beta - alpha)/beta;
      scal2 = 1.0/(alpha - beta);
    }
    if (g==0){ e[lo]=beta; tu[lo]=tau2; }
    bc[0]=tau2; bc[1]=scal2;
  }
  __syncthreads();
  double tau2 = bc[0], scal2 = bc[1];
  // sweep owned rows (global A): A -= v w^T + w v^T ; acc = A_new*v2
  // (v2 derived on the fly); export column lo2 into colW.
  {
    double vvc[8], wvc[8], v2c[8];
    #pragma unroll
    for (int j=0;j<8;j++){
      int c = lo + lane + 64*j;
      bool ok = c < 512;
      vvc[j] = ok ? vv[c] : 0.0;
      wvc[j] = ok ? wv[c] : 0.0;
      double v2v = 0.0;
      if (ok){
        if (c==lo2) v2v = 1.0;
        else if (c>lo2) v2v = (tau2==0.0) ? 0.0 : col2[c]*scal2;
      }
      v2c[j] = v2v;
    }
    int r0 = lo + ((g - lo) & 15);
    for (int r = r0 + 16*wave; r < 512; r += 64){
      double* Ar = A + (size_t)r*512;
      double vr = vv[r], wr = wv[r];
      double p = 0.0;
      #pragma unroll
      for (int j=0;j<8;j++){
        int c = lo + lane + 64*j;
        if (c < 512){
          double an = Ar[c] - vr*wvc[j] - wr*vvc[j];
          Ar[c] = an;
          p += an * v2c[j];
          if (c == lo2) colW[r] = an;
        }
      }
      #pragma unroll
      for (int off=32; off; off>>=1) p += __shfl_down(p, off, 64);
      if (lane==0) accW[r] = p;
    }
  }
  // v2 publish (owned rows) + V write
  for (int r=t; r<512; r+=256){
    if (r>=lo2 && (r&15)==g){
      double v = 0.0;
      if (r==lo2) v = 1.0;
      else v = (tau2==0.0) ? 0.0 : col2[r]*scal2;
      vvW[r] = v;
      V[(size_t)lo*512 + r] = v;
    }
  }
}

__global__ void k_diag(const double* A8, double* smalls){
  int sg = blockIdx.x, t = threadIdx.x;
  const double* A = A8 + (size_t)sg*MATSZ;
  double* d = smalls + (size_t)sg*512;
  for (int r=t; r<512; r+=256) d[r] = A[(size_t)r*512 + r];
}

// sstedc-style pre-scale: org = max(|d|,|e|); d,e /= org
__global__ void k_scale(double* smalls, int sbase){
  int sg = sbase + blockIdx.x, t = threadIdx.x;
  double* d = smalls + (size_t)sg*512;
  double* e = smalls + 4096 + (size_t)sg*512;
  __shared__ double red[256];
  double m = 0.0;
  for (int i=t;i<512;i+=256) m = fmax(m, fabs(d[i]));
  for (int i=t;i<511;i+=256) m = fmax(m, fabs(e[i]));
  red[t]=m; __syncthreads();
  for (int off=128; off; off>>=1){ if (t<off) red[t]=fmax(red[t],red[t+off]); __syncthreads(); }
  double org = red[0]; if (org == 0.0) org = 1.0;
  if (t==0) smalls[12288+sg] = org;
  double inv = 1.0/org;
  __syncthreads();
  for (int i=t;i<512;i+=256) d[i] *= inv;
  for (int i=t;i<511;i+=256) e[i] *= inv;
}

__global__ void k_tear(double* smalls, int sbase){
  int t = threadIdx.x;           // 128 threads: s = t>>5, k = (t&31)+1
  int sg = sbase + (t >> 5), k = (t & 31) + 1;
  if (k <= 31){
    double* d = smalls + (size_t)sg*512;
    double* e = smalls + 4096 + (size_t)sg*512;
    double ae = fabs(e[16*k - 1]);
    d[16*k - 1] -= ae;
    d[16*k]     -= ae;
  }
}

// 32 leaves of 16 per matrix; 8 leaves per block, threads 0..7 active
__global__ __launch_bounds__(64) void k_leaves(double* smalls, double* Zb, int sbase){
  __shared__ double LA[8][256];
  __shared__ double LQ[8][256];
  int t = threadIdx.x;
  if (t < 8){
    int bid = blockIdx.x;        // 0..15
    int s_local = bid >> 2;
    int sg = sbase + s_local;
    int leaf = (bid & 3)*8 + t;  // 0..31
    double* d = smalls + (size_t)sg*512;
    double* e = smalls + 4096 + (size_t)sg*512;
    double* Z = Zb + (size_t)s_local*MATSZ;
    int base = leaf*16;
    double* A = LA[t]; double* Q = LQ[t];
    for (int i=0;i<256;i++){ A[i]=0.0; Q[i]=0.0; }
    for (int i=0;i<16;i++){ A[i*17] = d[base+i]; Q[i*17] = 1.0; }
    for (int i=0;i<15;i++){ double ee = e[base+i]; A[i*16+i+1] = ee; A[(i+1)*16+i] = ee; }
    double nrm = 0.0;
    for (int i=0;i<256;i++) nrm += A[i]*A[i];
    double thr = nrm*1e-30 + 1e-300;
    for (int sweep=0; sweep<60; sweep++){
      double off = 0.0;
      for (int p=0;p<15;p++) for (int q=p+1;q<16;q++){
        double apq = A[p*16+q];
        off += 2.0*apq*apq;
        if (apq == 0.0) continue;
        double theta = 0.5*(A[q*17]-A[p*17])/apq;
        double tt;
        if (fabs(theta) > 1e18) tt = 0.5/theta;
        else tt = copysign(1.0, theta)/(fabs(theta)+sqrt(theta*theta+1.0));
        double cc = 1.0/sqrt(tt*tt+1.0), ss = tt*cc;
        for (int k=0;k<16;k++){
          double akp=A[k*16+p], akq=A[k*16+q];
          A[k*16+p] = cc*akp - ss*akq;
          A[k*16+q] = ss*akp + cc*akq;
        }
        for (int k=0;k<16;k++){
          double apk=A[p*16+k], aqk=A[q*16+k];
          A[p*16+k] = cc*apk - ss*aqk;
          A[q*16+k] = ss*apk + cc*aqk;
        }
        for (int k=0;k<16;k++){
          double qkp=Q[k*16+p], qkq=Q[k*16+q];
          Q[k*16+p] = cc*qkp - ss*qkq;
          Q[k*16+q] = ss*qkp + cc*qkq;
        }
      }
      if (off < thr) break;
    }
    for (int i=0;i<16;i++){
      int mi=i;
      for (int j=i+1;j<16;j++) if (A[j*17] < A[mi*17]) mi=j;
      if (mi!=i){
        double tmp=A[i*17]; A[i*17]=A[mi*17]; A[mi*17]=tmp;
        for (int k=0;k<16;k++){ double q1=Q[k*16+i]; Q[k*16+i]=Q[k*16+mi]; Q[k*16+mi]=q1; }
      }
    }
    for (int i=0;i<16;i++) d[base+i] = A[i*17];
    for (int r=0;r<16;r++)
      for (int c=0;c<16;c++)
        Z[(size_t)(base+r)*512 + base + c] = Q[r*16+c];
  }
}

// one block per merge: LAPACK slaed2 deflation + secular solve + Gu-Eisenstat
__global__ __launch_bounds__(256) void k_secular(double* smalls, const double* Zsrc_b,
                                                 double* Sm_b, int level, int sbase){
  const double EPS32 = 5.9604644775390625e-8;   // SLAMCH('E') for f32
  const double ISQ2  = 0.70710678118654752440;
  int s_local = blockIdx.x;
  int sg = sbase + s_local;
  int hh = 16 << level, n = hh << 1;
  int merge = blockIdx.y, start = merge*n;
  double* d = smalls + (size_t)sg*512;
  const double* e = smalls + 4096 + (size_t)sg*512;
  const double* Z = Zsrc_b + (size_t)s_local*MATSZ;
  double* Sm = Sm_b + (size_t)s_local*MATSZ;
  double* rotg = smalls + 12544 + (size_t)(sg*32+merge)*1024;
  __shared__ double ds[512], zl[512], dk[512], zk[512], tauk[512], zh[512], outlam[512];
  __shared__ double rc[256], rs[256];
  __shared__ double red[256];
  __shared__ double sv[2];
  __shared__ int perm[512], kidx[512], Ksk[512], didx[512], outid[512];
  __shared__ int rp[256], rq[256];
  __shared__ int counts[3];
  int t = threadIdx.x;
  if (t == 0){
    int i=0, j=hh, k=0;
    while (i < hh && j < n){
      if (d[start+i] <= d[start+j]) perm[k++]=i++; else perm[k++]=j++;
    }
    while (i < hh) perm[k++]=i++;
    while (j < n)  perm[k++]=j++;
  }
  __syncthreads();
  double eb = e[start+hh-1];
  double rho = 2.0*fabs(eb);
  double sgn = (eb < 0.0) ? -1.0 : 1.0;
  for (int i=t; i<n; i+=NT){
    int p = perm[i];
    ds[i] = d[start+p];
    double zr = (p < hh) ? Z[(size_t)(start+hh-1)*512 + start + p]
                         : sgn * Z[(size_t)(start+hh)*512 + start + p];
    zl[i] = zr * ISQ2;
  }
  __syncthreads();
  double m = 0.0;
  for (int i=t;i<n;i+=NT) m = fmax(m, fabs(zl[i]));
  red[t]=m; __syncthreads();
  for (int off=128; off; off>>=1){ if (t<off) red[t]=fmax(red[t],red[t+off]); __syncthreads(); }
  if (t==0) sv[0] = red[0];
  __syncthreads();
  m = 0.0;
  for (int i=t;i<n;i+=NT) m = fmax(m, fabs(ds[i]));
  red[t]=m; __syncthreads();
  for (int off=128; off; off>>=1){ if (t<off) red[t]=fmax(red[t],red[t+off]); __syncthreads(); }
  if (t==0) sv[1] = red[0];
  __syncthreads();
  double zmaxv = sv[0];
  double tol = 8.0*EPS32*fmax(sv[1], zmaxv);

  if (t == 0){
    int K=0, nd=0, nrot=0;
    if (rho*zmaxv <= tol){
      for (int j=0;j<n;j++) didx[nd++]=j;
    } else {
      int pj = -1;
      for (int j=0;j<n;j++){
        if (rho*fabs(zl[j]) <= tol){
          didx[nd++]=j;
        } else if (pj < 0){
          pj = j;
        } else {
          double s_ = zl[pj], c_ = zl[j];
          double tau2 = sqrt(c_*c_ + s_*s_);
          double tdf = ds[j] - ds[pj];
          double cc = c_/tau2, sr = -s_/tau2;
          if (fabs(tdf*cc*sr) <= tol){
            zl[j] = tau2; zl[pj] = 0.0;
            if (nrot < 256){
              rp[nrot]=perm[pj]; rq[nrot]=perm[j]; rc[nrot]=cc; rs[nrot]=sr; nrot++;
            }
            double tn = ds[pj]*cc*cc + ds[j]*sr*sr;
            ds[j]  = ds[pj]*sr*sr + ds[j]*cc*cc;
            ds[pj] = tn;
            didx[nd++] = pj;
            pj = j;
          } else {
            kidx[K++] = pj;
            pj = j;
          }
        }
      }
      if (pj >= 0) kidx[K++] = pj;
    }
    for (int a=1;a<nd;a++){
      int v = didx[a]; double dv = ds[v]; int b = a-1;
      while (b >= 0 && ds[didx[b]] > dv){ didx[b+1]=didx[b]; b--; }
      didx[b+1] = v;
    }
    counts[0]=K; counts[1]=nd; counts[2]=nrot;
    rotg[0] = (double)nrot;
    for (int i=0;i<nrot;i++){
      rotg[1+4*i]=(double)rp[i]; rotg[2+4*i]=(double)rq[i];
      rotg[3+4*i]=rc[i]; rotg[4+4*i]=rs[i];
    }
  }
  __syncthreads();
  int K = counts[0], nd = counts[1];

  for (int k=t; k<K; k+=NT){ dk[k]=ds[kidx[k]]; zk[k]=zl[kidx[k]]; }
  __syncthreads();

  for (int j2=t; j2<K; j2+=NT){
    int Kb; double lo, hi;
    if (j2 < K-1){
      double mid = 0.5*(dk[j2+1]-dk[j2]);
      double gg = 1.0;
      for (int i=0;i<K;i++){ double dif=(dk[i]-dk[j2])-mid; gg += rho*zk[i]*zk[i]/dif; }
      if (gg >= 0.0){ Kb=j2;   lo=0.0;  hi=mid; }
      else          { Kb=j2+1; lo=-mid; hi=0.0; }
    } else {
      double sz=0.0;
      for (int i=0;i<K;i++) sz += zk[i]*zk[i];
      Kb=K-1; lo=0.0; hi=rho*sz + 1e-300;
    }
    double dK = dk[Kb];
    for (int it=0; it<72; it++){
      double mid = 0.5*(lo+hi);
      if (mid==lo || mid==hi) break;
      double gg = 1.0;
      for (int i=0;i<K;i++){ double dif=(dk[i]-dK)-mid; gg += rho*zk[i]*zk[i]/dif; }
      if (gg < 0.0) lo=mid; else hi=mid;
    }
    Ksk[j2]=Kb; tauk[j2]=0.5*(lo+hi);
  }
  __syncthreads();
  for (int i=t; i<K; i+=NT){
    double P = (Ksk[i]==i) ? tauk[i] : (dk[Ksk[i]]-dk[i]) + tauk[i];
    for (int j=0;j<K;j++){
      if (j==i) continue;
      double num = (dk[Ksk[j]]-dk[i]) + tauk[j];
      double den = dk[j]-dk[i];
      P *= num/den;
    }
    zh[i] = copysign(sqrt(fabs(P/rho)), zk[i]);
  }
  __syncthreads();
  if (t == 0){
    int a=0, b=0;
    for (int j=0;j<n;j++){
      double la = (a<K)  ? (dk[Ksk[a]]+tauk[a]) : 1e300;
      double lb = (b<nd) ? ds[didx[b]]          : 1e300;
      if (la <= lb){ outid[j]=a;     outlam[j]=la; a++; }
      else         { outid[j]=512+b; outlam[j]=lb; b++; }
    }
  }
  __syncthreads();
  for (int j=t; j<n; j+=NT) d[start+j] = outlam[j];
  for (int j=t; j<n; j+=NT){
    double* col = Sm + (size_t)(start+j)*512;
    int id = outid[j];
    for (int i=0;i<n;i++) col[i]=0.0;
    if (id >= 512){
      col[perm[didx[id-512]]] = 1.0;
    } else {
      int k = id;
      double ss_ = 0.0;
      for (int i=0;i<K;i++){
        double dif = (dk[i]-dk[Ksk[k]]) - tauk[k];
        if (dif == 0.0) dif = 1e-300;
        double v = zh[i]/dif;
        col[perm[kidx[i]]] = v; ss_ += v*v;
      }
      double inv = 1.0/sqrt(ss_);
      for (int i=0;i<K;i++) col[perm[kidx[i]]] *= inv;
    }
  }
}

// apply recorded Givens rotations to S rows (reverse order)
__global__ __launch_bounds__(256) void k_rot(double* Sm_b, const double* smalls,
                                             int level, int sbase){
  int s_local = blockIdx.x, merge = blockIdx.y;
  int sg = sbase + s_local;
  int hh = 16 << level, n = hh << 1, start = merge*n;
  const double* rotg = smalls + 12544 + (size_t)(sg*32+merge)*1024;
  double* Sm = Sm_b + (size_t)s_local*MATSZ;
  int cnt = (int)rotg[0];
  for (int i=cnt-1; i>=0; i--){
    int p = (int)rotg[1+4*i], q = (int)rotg[2+4*i];
    double c = rotg[3+4*i], sr = rotg[4+4*i];
    for (int j=threadIdx.x; j<n; j+=256){
      double* col = Sm + (size_t)(start+j)*512;
      double a = col[p], b = col[q];
      col[p] = c*a - sr*b;
      col[q] = sr*a + c*b;
    }
    __syncthreads();
  }
}

// Zdst[merge square] = Zsrc[:,local-cols] * S
__global__ __launch_bounds__(256) void k_gemm64(const double* Zsrc_b, const double* Sm_b,
                                                double* Zdst_b, int level){
  int hh = 16 << level, n = hh << 1;
  int mpm = 512 / n;
  int bz = blockIdx.z;
  int s = bz / mpm, merge = bz % mpm;
  int start = merge*n;
  const double* Zs = Zsrc_b + (size_t)s*MATSZ;
  const double* Sm = Sm_b + (size_t)s*MATSZ;
  double* Zd = Zdst_b + (size_t)s*MATSZ;
  int row0 = start + blockIdx.y*32, col0 = start + blockIdx.x*32;
  int t = threadIdx.x;
  int tr = t >> 4, tc = t & 15;
  __shared__ double As[32][33];
  __shared__ double Bs[32][33];
  double a00=0,a01=0,a10=0,a11=0;
  for (int q0=0; q0<n; q0+=32){
    #pragma unroll
    for (int it=0; it<4; it++){
      int idx = t + it*256;
      int r = idx >> 5, q = idx & 31;
      As[r][q] = Zs[(size_t)(row0+r)*512 + start + q0 + q];
    }
    #pragma unroll
    for (int it=0; it<4; it++){
      int idx = t + it*256;
      int c = idx >> 5, q = idx & 31;
      Bs[q][c] = Sm[(size_t)(col0+c)*512 + q0 + q];
    }
    __syncthreads();
    #pragma unroll 8
    for (int q=0;q<32;q++){
      double ar0=As[tr][q], ar1=As[tr+16][q];
      double bc0=Bs[q][tc], bc1=Bs[q][tc+16];
      a00 = fma(ar0,bc0,a00); a01 = fma(ar0,bc1,a01);
      a10 = fma(ar1,bc0,a10); a11 = fma(ar1,bc1,a11);
    }
    __syncthreads();
  }
  Zd[(size_t)(row0+tr)*512 + col0+tc]       = a00;
  Zd[(size_t)(row0+tr)*512 + col0+tc+16]    = a01;
  Zd[(size_t)(row0+tr+16)*512 + col0+tc]    = a10;
  Zd[(size_t)(row0+tr+16)*512 + col0+tc+16] = a11;
}

// apply Q = H(1)...H(n-1) to Z from the left (reverse reflector order)
__global__ __launch_bounds__(256) void k_backq(double* Z2_b, const double* Vh_b,
                                               const double* smalls, int sbase){
  int s_local = blockIdx.x, cb = blockIdx.y;
  int sg = sbase + s_local;
  double* Z = Z2_b + (size_t)s_local*MATSZ;
  const double* V = Vh_b + (size_t)sg*MATSZ;
  const double* tu = smalls + 8192 + (size_t)sg*512;
  int cg = threadIdx.x >> 5, lane = threadIdx.x & 31;
  int c = cb*8 + cg;
  __shared__ double zc[8][512];
  for (int r=lane; r<512; r+=32) zc[cg][r] = Z[(size_t)r*512 + c];
  for (int i=509; i>=0; i--){
    double tv = tu[i];
    if (tv == 0.0) continue;
    double wp = 0.0;
    for (int r=i+1+lane; r<512; r+=32) wp += V[(size_t)i*512 + r]*zc[cg][r];
    #pragma unroll
    for (int off=16; off; off>>=1) wp += __shfl_down(wp, off, 32);
    double w = __shfl(wp, 0, 32);
    double tw = tv*w;
    for (int r=i+1+lane; r<512; r+=32) zc[cg][r] -= tw*V[(size_t)i*512 + r];
  }
  for (int r=lane; r<512; r+=32) Z[(size_t)r*512 + c] = zc[cg][r];
}

__global__ void k_finalize(const double* Z2_b, const double* smalls,
                           float* Vt_pass, float* eig, int pass, int sbase){
  int s_local = blockIdx.x;
  int sg = sbase + s_local;
  const double* Z = Z2_b + (size_t)s_local*MATSZ;
  double org = smalls[12288+sg];
  int idx = blockIdx.y*256 + threadIdx.x;   // < 262144
  int r = idx >> 9, c = idx & 511;
  Vt_pass[(size_t)s_local*MATSZ + (size_t)c*512 + r] = (float)Z[(size_t)r*512 + c];
  if (idx < 512)
    eig[(size_t)(pass*4+s_local)*512 + idx] = (float)(smalls[(size_t)sg*512 + idx]*org);
}

// --------------------------- diffusion (f32) --------------------------------
struct KArgs {
  const float* Vt;      // speaker Vt32 (4 slots)
  const float* Vt2;     // temporal Vt32 (4 slots)
  float *xspec, *hbuf, *x, *E;
  const float *W1s, *W1t, *W2s, *W2t;
  const float *b2s, *b2t, *wts, *wtt, *b1s, *b1t, *wes, *wet;
  const float *cond, *Wcs, *Wct;
  const float *eig;
  const float *rec, *recW, *recb;
  float* out;
  float t, a, bc;
  unsigned nk0, nk1, nk2, nk3;   // threefry step keys (speaker, temporal)
  int mode;
};

__global__ __launch_bounds__(256) void k_gemm32(KArgs P){
  int t = threadIdx.x;
  int tr = t >> 4, tc = t & 15;
  int bz = blockIdx.z;
  int m0 = blockIdx.y << 6, n0 = blockIdx.x << 6;
  const float *A, *B; float *C;
  int lda, K, chain = 0;
  if (P.mode == 0){
    A = (bz < 4) ? (P.Vt + (size_t)bz*MATSZ) : (P.Vt2 + (size_t)(bz-4)*MATSZ);
    lda = 512; K = 512;
    B = P.x + (size_t)bz*SZF; C = P.xspec + (size_t)bz*SZF;
  } else if (P.mode == 1){
    chain = bz >> 2;
    A = P.xspec + (size_t)bz*SZF; lda = 256; K = 256;
    B = chain ? P.W1t : P.W1s; C = P.hbuf + (size_t)bz*SZF;
  } else if (P.mode == 2){
    chain = bz >> 2;
    A = P.hbuf + (size_t)bz*SZF; lda = 256; K = 256;
    B = chain ? P.W2t : P.W2s; C = P.x + (size_t)bz*SZF;
  } else if (P.mode == 3){
    chain = bz;
    A = P.cond; lda = 256; K = 256;
    B = chain ? P.Wct : P.Wcs; C = P.E + (size_t)chain*4*SZF;
  } else {
    A = P.rec; lda = 256; K = 256;
    B = P.recW; C = P.out;
  }
  __shared__ float As[16][65];
  __shared__ float Bs[16][65];
  float acc[4][4] = {{0}};
  for (int k0=0; k0<K; k0+=16){
    #pragma unroll
    for (int it=0; it<4; it++){
      int idx = t + it*256;
      int r = idx >> 4, kk = idx & 15;
      As[kk][r] = A[(size_t)(m0 + r)*lda + k0 + kk];
    }
    #pragma unroll
    for (int it=0; it<4; it++){
      int idx = t + it*256;
      int c = idx & 63, kk = idx >> 6;
      Bs[kk][c] = B[(size_t)(k0 + kk)*256 + n0 + c];
    }
    __syncthreads();
    #pragma unroll
    for (int kk=0; kk<16; kk++){
      float ar[4], bv[4];
      #pragma unroll
      for (int q=0;q<4;q++){ ar[q] = As[kk][tr + (q<<4)]; bv[q] = Bs[kk][tc + (q<<4)]; }
      #pragma unroll
      for (int q=0;q<4;q++)
        #pragma unroll
        for (int p=0;p<4;p++)
          acc[q][p] = fmaf(ar[q], bv[p], acc[q][p]);
    }
    __syncthreads();
  }
  #pragma unroll
  for (int q=0;q<4;q++){
    #pragma unroll
    for (int p=0;p<4;p++){
      int r = m0 + tr + (q<<4);
      int c = n0 + tc + (p<<4);
      size_t oi = (size_t)r*256 + c;
      float v = acc[q][p];
      if (P.mode == 1){
        v += P.E[(size_t)bz*SZF + oi] + P.t * ((chain ? P.wtt : P.wts)[c]);
        float sg = 1.0f/(1.0f + expf(-v));
        v = v * sg;
      } else if (P.mode == 2){
        float bias = (chain ? P.b2t : P.b2s)[c];
        unsigned j = ((unsigned)(bz & 3))*131072u + (unsigned)oi;
        unsigned kk0 = chain ? P.nk2 : P.nk0;
        unsigned kk1 = chain ? P.nk3 : P.nk1;
        unsigned y0, y1;
        tf2x32(kk0, kk1, 0u, j, &y0, &y1);
        float nz = bits_to_normal(y0 ^ y1);
        v = C[oi] + P.a*(v + bias) + P.bc*nz;
      } else if (P.mode == 3){
        int bb = r >> 9, s2 = r & 511;
        v += (chain ? P.b1t : P.b1s)[c]
           + P.eig[(size_t)(chain*4 + bb)*512 + s2] * ((chain ? P.wet : P.wes)[c]);
      } else if (P.mode == 4){
        v += P.recb[c];
      }
      C[oi] = v;
    }
  }
}

__global__ void k_cond(float* cond, const float* a, const float* v){
  size_t i = (size_t)blockIdx.x*256 + threadIdx.x;
  cond[i] = 0.5f*(a[i] + v[i]);
}

__global__ void k_xinit(float* x, const float* xT){
  size_t i = (size_t)blockIdx.x*256 + threadIdx.x;
  size_t b = i >> 17, off = i & 131071;
  x[i] = xT[((b & 3) << 17) + off];
}

__global__ void k_rec(float* rec, const float* x){
  size_t i = (size_t)blockIdx.x*256 + threadIdx.x;
  rec[i] = 0.5f*(x[i] + x[i + 524288]);
}

__global__ void k_copy(float* out, const float* a, const float* v){
  size_t i = (size_t)blockIdx.x*256 + threadIdx.x;
  out[524288 + i] = (i < 524288) ? a[i] : v[i - 524288];
}

// ------------------------------- host --------------------------------------
extern "C" void kernel_launch(void* const* d_in, const int* in_sizes, int n_in,
                              void* d_out, int out_size, void* d_ws, size_t ws_size,
                              hipStream_t stream){
  const float* f_audio   = (const float*)d_in[1];
  const float* f_visual  = (const float*)d_in[2];
  const float* g_speaker = (const float*)d_in[3];
  const float* g_temporal= (const float*)d_in[4];
  const float* x_T       = (const float*)d_in[6];
  const float* tsW1=(const float*)d_in[7],  *tswe=(const float*)d_in[8],
             * tswt=(const float*)d_in[9],  *tsb1=(const float*)d_in[10],
             * tsWc=(const float*)d_in[11], *tsW2=(const float*)d_in[12],
             * tsb2=(const float*)d_in[13];
  const float* ttW1=(const float*)d_in[14], *ttwe=(const float*)d_in[15],
             * ttwt=(const float*)d_in[16], *ttb1=(const float*)d_in[17],
             * ttWc=(const float*)d_in[18], *ttW2=(const float*)d_in[19],
             * ttb2=(const float*)d_in[20];
  const float* recW=(const float*)d_in[21], *recb=(const float*)d_in[22];
  float* out = (float*)d_out;

  const size_t MB = 1ull << 20;
  if (ws_size < 43*MB) return;

  char* ws = (char*)d_ws;
  double* Vh     = (double*)(ws + 0);        // 8 slots, 16 MB
  double* A8     = (double*)(ws + 16*MB);    // 8 slots, 16 MB (dead after sytd2)
  double* A64    = (double*)(ws + 16*MB);    // D&C overlay
  double* Zb     = (double*)(ws + 24*MB);
  double* Sm     = (double*)(ws + 32*MB);
  double* smalls = (double*)(ws + 40*MB);
  float* Vt32_s  = (float*)(ws + 0);         // overlays V slots 0-1 (pass0)
  float* Vt32_t  = (float*)(ws + 8*MB);      // overlays V slots 4-5 (pass1)
  float* eig32   = (float*)(ws + 42*MB + 512*1024);
  // diffusion overlay (dead A8/D&C region after eigh)
  float* cond  = (float*)(ws + 16*MB);
  float* E     = (float*)(ws + 18*MB);
  float* xall  = (float*)(ws + 22*MB);
  float* xspec = (float*)(ws + 26*MB);
  float* hbuf  = (float*)(ws + 30*MB);

  // ---- jax.random key schedule (host, exact threefry, PARTITIONABLE) ----
  unsigned f0, f1;
  tf2x32(0u, 42u, 0u, 0u, &f0, &f1);                 // fold_in(key(42), 0)
  unsigned s0,s1,t0,t1;
  tf2x32(f0, f1, 0u, 0u, &s0, &s1);                  // k_s = split[0]
  tf2x32(f0, f1, 0u, 1u, &t0, &t1);                  // k_t = split[1]
  unsigned skeys[100][2], tkeys[100][2];
  for (int k=0; k<100; k++){
    tf2x32(s0, s1, 0u, (unsigned)k, &skeys[k][0], &skeys[k][1]);
    tf2x32(t0, t1, 0u, (unsigned)k, &tkeys[k][0], &tkeys[k][1]);
  }

  // ---- eigh: sytd2 via 510 per-column launches (all 8 matrices batched) ----
  k_prep8<<<8192, 256, 0, stream>>>(A8, g_speaker, g_temporal);
  k_sy_init_a<<<8, 256, 0, stream>>>(g_speaker, g_temporal, Vh, smalls);
  k_sy_init_b<<<128, 256, 0, stream>>>(A8, smalls);
  for (int i=0; i<510; i++)
    k_sy_step<<<128, 256, 0, stream>>>(A8, Vh, smalls, i);
  k_diag<<<8, 256, 0, stream>>>(A8, smalls);

  for (int pass=0; pass<2; pass++){
    int sbase = 4*pass;
    k_scale<<<4, 256, 0, stream>>>(smalls, sbase);
    hipMemsetAsync(Zb, 0, 8*MB, stream);
    hipMemsetAsync(A64, 0, 8*MB, stream);
    k_tear<<<1, 128, 0, stream>>>(smalls, sbase);
    k_leaves<<<16, 64, 0, stream>>>(smalls, Zb, sbase);
    for (int level=0; level<5; level++){
      int n = 32 << level, mpm = 512/n;
      double* src = (level & 1) ? A64 : Zb;
      double* dst = (level & 1) ? Zb  : A64;
      k_secular<<<dim3(4, mpm), 256, 0, stream>>>(smalls, src, Sm, level, sbase);
      k_rot<<<dim3(4, mpm), 256, 0, stream>>>(Sm, smalls, level, sbase);
      k_gemm64<<<dim3(n/32, n/32, 4*mpm), 256, 0, stream>>>(src, Sm, dst, level);
    }
    k_backq<<<dim3(4, 64), 256, 0, stream>>>(A64, Vh, smalls, sbase);
    k_finalize<<<dim3(4, 1024), 256, 0, stream>>>(A64, smalls,
                                                  pass ? Vt32_t : Vt32_s,
                                                  eig32, pass, sbase);
  }

  // ---- diffusion ----
  k_cond<<<2048, 256, 0, stream>>>(cond, f_audio, f_visual);
  k_xinit<<<4096, 256, 0, stream>>>(xall, x_T);

  KArgs P;
  P.Vt = Vt32_s; P.Vt2 = Vt32_t;
  P.xspec = xspec; P.hbuf = hbuf; P.x = xall; P.E = E;
  P.W1s = tsW1; P.W1t = ttW1; P.W2s = tsW2; P.W2t = ttW2;
  P.b2s = tsb2; P.b2t = ttb2; P.wts = tswt; P.wtt = ttwt;
  P.b1s = tsb1; P.b1t = ttb1; P.wes = tswe; P.wet = ttwe;
  P.cond = cond; P.Wcs = tsWc; P.Wct = ttWc;
  P.eig = eig32; P.rec = xspec; P.recW = recW; P.recb = recb; P.out = out;
  P.t = 0.f; P.a = 0.f; P.bc = 0.f;
  P.nk0 = 0; P.nk1 = 0; P.nk2 = 0; P.nk3 = 0;

  P.mode = 3;
  k_gemm32<<<dim3(4, 32, 2), 256, 0, stream>>>(P);

  for (int k=0; k<100; k++){
    float tf = (float)(1.0 - (double)k/99.0);
    float av = (float)(pow(25.0, 2.0*(double)tf) * 0.01);
    float bcv = (float)(pow(25.0, (double)tf) * 0.1);
    P.nk0 = skeys[k][0]; P.nk1 = skeys[k][1];
    P.nk2 = tkeys[k][0]; P.nk3 = tkeys[k][1];
    P.mode = 0;
    k_gemm32<<<dim3(4, 8, 8), 256, 0, stream>>>(P);
    P.mode = 1; P.t = tf;
    k_gemm32<<<dim3(4, 8, 8), 256, 0, stream>>>(P);
    P.mode = 2; P.a = av; P.bc = bcv;
    k_gemm32<<<dim3(4, 8, 8), 256, 0, stream>>>(P);
  }

  k_rec<<<2048, 256, 0, stream>>>(xspec, xall);
  P.mode = 4; P.rec = xspec;
  k_gemm32<<<dim3(4, 32, 1), 256, 0, stream>>>(P);
  k_copy<<<4096, 256, 0, stream>>>(out, f_audio, f_visual);
}

// Round 13
// 37778.760 us; speedup vs baseline: 1.1362x; 1.1362x over previous
//
#include <hip/hip_runtime.h>
#include <math.h>
#include <stdint.h>

// ---------------------------------------------------------------------------
// DualSpectralDiffusion: faithful replication of the JAX reference.
//  - f64 eigh: persistent multi-block sytd2 (A in LDS, fence-free epoch
//    barrier) for columns 0..383 + single-block-per-matrix LDS tail for
//    columns 384..509; D&C w/ slaed2 deflation mimicry (sign-faithful).
//  - exact threefry2x32 / jax.random replication (PARTITIONABLE stream)
//  - f32 diffusion loop, vectorized (b128-LDS) GEMM, threefry in epilogue
// ---------------------------------------------------------------------------

#define NT 256
#define SZF 131072          // 512*256 floats per (b) tensor
#define MATSZ 262144        // 512*512
#define NB 32               // sytd2 blocks per matrix (16 rows each, in LDS)
#define ILAST 384           // persistent kernel handles i in [0,ILAST)
#define TBASE (ILAST+1)     // 385
#define TSZ (512-TBASE)     // 127

#define ALD(p)    __hip_atomic_load((p),  __ATOMIC_RELAXED, __HIP_MEMORY_SCOPE_AGENT)
#define AST(p,v)  __hip_atomic_store((p), (v), __ATOMIC_RELAXED, __HIP_MEMORY_SCOPE_AGENT)

// ws layout (bytes):
//   V (f64, 8 slots)   [0,16MB)   Vt32 overlays: pass0 [0,4MB), pass1 [8,12MB)
//   Atail/A64dc        [16,24MB)  Zb [24,32MB)  Sm [32,40MB)
//   smalls             [40MB,~42.4MB)   eig32 @42.5MB
//   diffusion overlay: cond@16MB, E@18, xall@22, xspec@26, hbuf@30
// smalls (double idx): d@0, e@4096, tau@8192, org@12288,
//   rot@12544+(sg*32+m)*1024 (ends 274688), acc pp@274688(+4096),
//   col pp@282880(+4096), vvh@291072 (+4096=295168), slots(uint)@295168

// ----------------------------- threefry ------------------------------------
__host__ __device__ static inline unsigned rotl32(unsigned v, int r){ return (v<<r)|(v>>(32-r)); }

__host__ __device__ static inline void tf2x32(unsigned k0, unsigned k1,
                                              unsigned x0, unsigned x1,
                                              unsigned* o0, unsigned* o1){
  unsigned ks2 = k0 ^ k1 ^ 0x1BD11BDAu;
  x0 += k0; x1 += k1;
#define TF4(r0,r1,r2,r3) \
  x0 += x1; x1 = rotl32(x1,r0); x1 ^= x0; \
  x0 += x1; x1 = rotl32(x1,r1); x1 ^= x0; \
  x0 += x1; x1 = rotl32(x1,r2); x1 ^= x0; \
  x0 += x1; x1 = rotl32(x1,r3); x1 ^= x0;
  TF4(13,15,26,6)  x0 += k1;  x1 += ks2 + 1u;
  TF4(17,29,16,24) x0 += ks2; x1 += k0 + 2u;
  TF4(13,15,26,6)  x0 += k0;  x1 += k1 + 3u;
  TF4(17,29,16,24) x0 += k1;  x1 += ks2 + 4u;
  TF4(13,15,26,6)  x0 += ks2; x1 += k0 + 5u;
#undef TF4
  *o0 = x0; *o1 = x1;
}

// XLA ErfInv f32 polynomial; matches lax.erf_inv expansion.
__device__ static inline float erfinv_xla(float x){
  float w = -log1pf(-x*x);
  float p;
  if (w < 5.0f){
    w -= 2.5f;
    p = 2.81022636e-08f;
    p = fmaf(p, w, 3.43273939e-07f);
    p = fmaf(p, w, -3.5233877e-06f);
    p = fmaf(p, w, -4.39150654e-06f);
    p = fmaf(p, w, 0.00021858087f);
    p = fmaf(p, w, -0.00125372503f);
    p = fmaf(p, w, -0.00417768164f);
    p = fmaf(p, w, 0.246640727f);
    p = fmaf(p, w, 1.50140941f);
  } else {
    w = sqrtf(w) - 3.0f;
    p = -0.000200214257f;
    p = fmaf(p, w, 0.000100950558f);
    p = fmaf(p, w, 0.00134934322f);
    p = fmaf(p, w, -0.00367342844f);
    p = fmaf(p, w, 0.00573950773f);
    p = fmaf(p, w, -0.0076224613f);
    p = fmaf(p, w, 0.00943887047f);
    p = fmaf(p, w, 1.00167406f);
    p = fmaf(p, w, 2.83297682f);
  }
  return p*x;
}

__device__ static inline float bits_to_normal(unsigned bits){
  const float MINV = -0.99999994f;   // nextafter(-1,0) in f32
  float f = __uint_as_float((bits >> 9) | 0x3f800000u) - 1.0f;
  float u = fmaxf(MINV, fmaf(f, 2.0f, MINV));
  return 1.41421356237309515f * erfinv_xla(u);
}

// ------------------------------- eigh --------------------------------------
// FENCE-FREE per-matrix barrier (relaxed agent atomics, no cache maint.)
__device__ __forceinline__ void gbar2(unsigned* slots, int sg, int g, unsigned epoch){
  __threadfence_block();
  __syncthreads();
  int t = threadIdx.x;
  if (t == 0) AST(slots + (sg*NB + g)*16, epoch);
  if (t < NB){
    unsigned* sl = slots + (sg*NB + t)*16;
    while (ALD(sl) < epoch){ __builtin_amdgcn_s_sleep(1); }
  }
  __syncthreads();
}

// Persistent multi-block Householder head: columns 0..ILAST-1.
// 8 matrices x NB blocks; block g owns rows r%NB==g (LDS-resident).
__global__ __launch_bounds__(256) void k_sytd2_lds(const float* Gs, const float* Gt,
                                                   double* Vb, double* smalls,
                                                   unsigned* slots, double* Atail){
  int sg = blockIdx.x / NB, g = blockIdx.x % NB;
  const float* G = (sg < 4) ? (Gs + (size_t)sg*MATSZ) : (Gt + (size_t)(sg-4)*MATSZ);
  double* V = Vb + (size_t)sg*MATSZ;
  double* d  = smalls + (size_t)sg*512;
  double* e  = smalls + 4096 + (size_t)sg*512;
  double* tu = smalls + 8192 + (size_t)sg*512;
  double* acc0 = smalls + 274688 + (size_t)sg*512;
  double* acc1 = acc0 + 4096;
  double* col0 = smalls + 282880 + (size_t)sg*512;
  double* col1 = col0 + 4096;
  double* vvh  = smalls + 291072 + (size_t)sg*512;
  double* At = Atail + (size_t)sg*MATSZ;
  int t = threadIdx.x, wave = t >> 6, lane = t & 63;

  __shared__ double Arows[16][512];   // owned rows r = 32*j + g
  __shared__ double vv[512], wv[512], col2[512], acc[512];
  __shared__ double red[4];
  __shared__ double bc[4];

  for (int j=0; j<16; j++){
    int r = 32*j + g;
    for (int c=t; c<512; c+=256)
      Arows[j][c] = (double)G[(size_t)r*512 + c];
  }

  // ---------- init: reflector 0 (replicated) ----------
  for (int r=t; r<512; r+=256) col2[r] = (r>=1) ? (double)G[(size_t)r*512] : 0.0;
  __syncthreads();
  {
    double part = 0.0;
    for (int r=2+t; r<512; r+=256) part += col2[r]*col2[r];
    #pragma unroll
    for (int off=32; off; off>>=1) part += __shfl_down(part, off, 64);
    if (lane==0) red[wave]=part;
    __syncthreads();
    if (t==0){
      double xsq = red[0]+red[1]+red[2]+red[3];
      double alpha = col2[1];
      double beta,tv,scal;
      if (xsq == 0.0){ beta=alpha; tv=0.0; scal=0.0; }
      else {
        beta = -copysign(sqrt(alpha*alpha + xsq), alpha);   // LAPACK slarfg
        tv = (beta - alpha)/beta;
        scal = 1.0/(alpha - beta);
      }
      if (g==0){ e[0]=beta; tu[0]=tv; }
      bc[0]=tv; bc[1]=scal;
    }
  }
  __syncthreads();
  double tauv = bc[0];
  {
    double scal = bc[1];
    for (int r=t; r<512; r+=256){
      double v = 0.0;
      if (r==1) v = 1.0;
      else if (r>1) v = (tauv==0.0) ? 0.0 : col2[r]*scal;
      vv[r]=v;
      if (r>=1 && (r & (NB-1))==g) V[r] = v;
    }
  }
  __syncthreads();
  if (g==0){
    for (int r=1+t; r<512; r+=256) AST(&col0[r], (double)G[(size_t)r*512 + 1]);
  }
  {
    int r0 = 1 + ((g - 1) & (NB-1));
    for (int r = r0 + NB*wave; r < 512; r += 4*NB){
      const double* Ar = Arows[r>>5];
      double p = 0.0;
      for (int c=lane; c<512; c+=64) p += Ar[c]*vv[c];
      #pragma unroll
      for (int off=32; off; off>>=1) p += __shfl_down(p, off, 64);
      if (lane==0) AST(&acc0[r], p);
    }
  }

  // ---------- main loop (fused phases), i in [0, ILAST) ----------
  for (int i=0; i<ILAST; i++){
    gbar2(slots, sg, g, (unsigned)(i+1));
    int lo=i+1, lo2=i+2;
    double* accR = (i&1) ? acc1 : acc0;
    double* colR = (i&1) ? col1 : col0;
    double* accW = (i&1) ? acc0 : acc1;
    double* colW = (i&1) ? col0 : col1;
    double part = 0.0;
    for (int r=lo+t; r<512; r+=256){
      double a_ = ALD(&accR[r]);
      double c_ = ALD(&colR[r]);
      acc[r]=a_; col2[r]=c_;
      part += (tauv*a_)*vv[r];
    }
    #pragma unroll
    for (int off=32; off; off>>=1) part += __shfl_down(part, off, 64);
    if (lane==0) red[wave]=part;
    __syncthreads();
    if (t==0){ double dot=red[0]+red[1]+red[2]+red[3]; bc[2] = -0.5*tauv*dot; }
    __syncthreads();
    {
      double alpha2 = bc[2];
      double vlo = vv[lo];
      double wlo = fma(alpha2, vlo, tauv*acc[lo]);
      for (int r=lo+t; r<512; r+=256){
        double wr = fma(alpha2, vv[r], tauv*acc[r]);
        wv[r]=wr;
        col2[r] = col2[r] - vv[r]*wlo - wr*vlo;
      }
    }
    __syncthreads();
    part = 0.0;
    for (int r=lo2+1+t; r<512; r+=256) part += col2[r]*col2[r];
    #pragma unroll
    for (int off=32; off; off>>=1) part += __shfl_down(part, off, 64);
    if (lane==0) red[wave]=part;
    __syncthreads();
    if (t==0){
      double xsq = red[0]+red[1]+red[2]+red[3];
      double alpha = col2[lo2];
      double beta,tau2,scal2;
      if (xsq == 0.0){ beta=alpha; tau2=0.0; scal2=0.0; }
      else {
        beta = -copysign(sqrt(alpha*alpha + xsq), alpha);
        tau2 = (beta - alpha)/beta;
        scal2 = 1.0/(alpha - beta);
      }
      if (g==0){ e[lo]=beta; tu[lo]=tau2; }
      bc[0]=tau2; bc[1]=scal2;
    }
    __syncthreads();
    double tau2 = bc[0], scal2 = bc[1];
    {
      double vvc[8], wvc[8], v2c[8];
      #pragma unroll
      for (int j=0;j<8;j++){
        int c = lo + lane + 64*j;
        bool ok = c < 512;
        vvc[j] = ok ? vv[c] : 0.0;
        wvc[j] = ok ? wv[c] : 0.0;
        double v2v = 0.0;
        if (ok){
          if (c==lo2) v2v = 1.0;
          else if (c>lo2) v2v = (tau2==0.0) ? 0.0 : col2[c]*scal2;
        }
        v2c[j] = v2v;
      }
      int r0 = lo + ((g - lo) & (NB-1));
      for (int r = r0 + NB*wave; r < 512; r += 4*NB){
        double* Ar = Arows[r>>5];
        double vr = vv[r], wr = wv[r];
        double p = 0.0;
        #pragma unroll
        for (int j=0;j<8;j++){
          int c = lo + lane + 64*j;
          if (c < 512){
            double an = Ar[c] - vr*wvc[j] - wr*vvc[j];
            Ar[c] = an;
            p += an * v2c[j];
            if (c == lo2) AST(&colW[r], an);
          }
        }
        #pragma unroll
        for (int off=32; off; off>>=1) p += __shfl_down(p, off, 64);
        if (lane==0) AST(&accW[r], p);
      }
    }
    __syncthreads();
    for (int r=t; r<512; r+=256){
      double v = 0.0;
      if (r==lo2) v = 1.0;
      else if (r>lo2) v = (tau2==0.0) ? 0.0 : col2[r]*scal2;
      vv[r]=v;
      if (r>=lo2 && (r & (NB-1))==g) V[(size_t)lo*512 + r] = v;
    }
    tauv = tau2;
  }

  // ---------- handoff ----------
  // final diagonals for owned rows r <= ILAST
  if (t < 16){
    int r = 32*t + g;
    if (r <= ILAST) d[r] = Arows[t][r];
  }
  // trailing A rows (owned, r >= TBASE), cols [TBASE,512)
  for (int j=0; j<16; j++){
    int r = 32*j + g;
    if (r >= TBASE){
      for (int c=TBASE+t; c<512; c+=256)
        At[(size_t)r*512 + c] = Arows[j][c];
    }
  }
  // vv (reflector ILAST) published by g==0
  if (g==0){
    for (int r=t; r<512; r+=256) vvh[r] = vv[r];
  }
}

// Tail: columns ILAST..509, one block per matrix, A trailing in LDS,
// __syncthreads-only. Per-row/per-reduction mappings identical to head.
__global__ __launch_bounds__(256) void k_sy_tail(const double* Atail, double* Vb,
                                                 double* smalls){
  int sg = blockIdx.x;
  double* V = Vb + (size_t)sg*MATSZ;
  double* d  = smalls + (size_t)sg*512;
  double* e  = smalls + 4096 + (size_t)sg*512;
  double* tu = smalls + 8192 + (size_t)sg*512;
  const double* accG = smalls + 274688 + (size_t)sg*512;  // parity(ILAST)=even -> base
  const double* colG = smalls + 282880 + (size_t)sg*512;
  const double* vvG  = smalls + 291072 + (size_t)sg*512;
  const double* At0 = Atail + (size_t)sg*MATSZ;
  int t = threadIdx.x, wave = t >> 6, lane = t & 63;

  __shared__ double At[TSZ*128];
  __shared__ double vv[512], wv[512], col2[512], acc[512], accN[512], colN[512];
  __shared__ double red[4];
  __shared__ double bc[4];

  for (int rl=0; rl<TSZ; rl++)
    for (int cl=t; cl<TSZ; cl+=256)
      At[rl*128+cl] = At0[(size_t)(TBASE+rl)*512 + TBASE+cl];
  for (int r=TBASE-1+t; r<512; r+=256){   // need indices >= lo=TBASE? load from lo-1 safe
    if (r >= TBASE){ ; }
  }
  for (int r=t; r<512; r+=256){
    if (r >= ILAST+1){ vv[r]=vvG[r]; acc[r]=accG[r]; col2[r]=colG[r]; }
    else if (r == ILAST){ vv[r]=vvG[r]; acc[r]=accG[r]; col2[r]=colG[r]; }
  }
  double tauv = tu[ILAST];
  __syncthreads();

  for (int i=ILAST; i<510; i++){
    int lo=i+1, lo2=i+2;
    double part = 0.0;
    for (int r=lo+t; r<512; r+=256) part += (tauv*acc[r])*vv[r];
    #pragma unroll
    for (int off=32; off; off>>=1) part += __shfl_down(part, off, 64);
    if (lane==0) red[wave]=part;
    __syncthreads();
    if (t==0){ double dot=red[0]+red[1]+red[2]+red[3]; bc[2] = -0.5*tauv*dot; }
    __syncthreads();
    {
      double alpha2 = bc[2];
      double vlo = vv[lo];
      double wlo = fma(alpha2, vlo, tauv*acc[lo]);
      for (int r=lo+t; r<512; r+=256){
        double wr = fma(alpha2, vv[r], tauv*acc[r]);
        wv[r]=wr;
        col2[r] = col2[r] - vv[r]*wlo - wr*vlo;
      }
    }
    __syncthreads();
    part = 0.0;
    for (int r=lo2+1+t; r<512; r+=256) part += col2[r]*col2[r];
    #pragma unroll
    for (int off=32; off; off>>=1) part += __shfl_down(part, off, 64);
    if (lane==0) red[wave]=part;
    __syncthreads();
    if (t==0){
      double xsq = red[0]+red[1]+red[2]+red[3];
      double alpha = col2[lo2];
      double beta,tau2,scal2;
      if (xsq == 0.0){ beta=alpha; tau2=0.0; scal2=0.0; }
      else {
        beta = -copysign(sqrt(alpha*alpha + xsq), alpha);
        tau2 = (beta - alpha)/beta;
        scal2 = 1.0/(alpha - beta);
      }
      e[lo]=beta; tu[lo]=tau2;
      bc[0]=tau2; bc[1]=scal2;
    }
    __syncthreads();
    double tau2 = bc[0], scal2 = bc[1];
    {
      double vvc[8], wvc[8], v2c[8];
      #pragma unroll
      for (int j=0;j<8;j++){
        int c = lo + lane + 64*j;
        bool ok = c < 512;
        vvc[j] = ok ? vv[c] : 0.0;
        wvc[j] = ok ? wv[c] : 0.0;
        double v2v = 0.0;
        if (ok){
          if (c==lo2) v2v = 1.0;
          else if (c>lo2) v2v = (tau2==0.0) ? 0.0 : col2[c]*scal2;
        }
        v2c[j] = v2v;
      }
      for (int r = lo + wave; r < 512; r += 4){
        double* Ar = &At[(r-TBASE)*128];
        double vr = vv[r], wr = wv[r];
        double p = 0.0;
        #pragma unroll
        for (int j=0;j<8;j++){
          int c = lo + lane + 64*j;
          if (c < 512){
            double an = Ar[c-TBASE] - vr*wvc[j] - wr*vvc[j];
            Ar[c-TBASE] = an;
            p += an * v2c[j];
            if (c == lo2) colN[r] = an;
          }
        }
        #pragma unroll
        for (int off=32; off; off>>=1) p += __shfl_down(p, off, 64);
        if (lane==0) accN[r] = p;
      }
    }
    __syncthreads();
    for (int r=t; r<512; r+=256){
      if (r >= lo2){
        double v = (r==lo2) ? 1.0 : ((tau2==0.0) ? 0.0 : col2[r]*scal2);
        vv[r]=v;
        V[(size_t)lo*512 + r] = v;
        col2[r] = colN[r];
        acc[r] = accN[r];
      }
    }
    tauv = tau2;
    __syncthreads();
  }
  for (int rl=t; rl<TSZ; rl+=256) d[TBASE+rl] = At[rl*128+rl];
}

// sstedc-style pre-scale: org = max(|d|,|e|); d,e /= org
__global__ void k_scale(double* smalls, int sbase){
  int sg = sbase + blockIdx.x, t = threadIdx.x;
  double* d = smalls + (size_t)sg*512;
  double* e = smalls + 4096 + (size_t)sg*512;
  __shared__ double red[256];
  double m = 0.0;
  for (int i=t;i<512;i+=256) m = fmax(m, fabs(d[i]));
  for (int i=t;i<511;i+=256) m = fmax(m, fabs(e[i]));
  red[t]=m; __syncthreads();
  for (int off=128; off; off>>=1){ if (t<off) red[t]=fmax(red[t],red[t+off]); __syncthreads(); }
  double org = red[0]; if (org == 0.0) org = 1.0;
  if (t==0) smalls[12288+sg] = org;
  double inv = 1.0/org;
  __syncthreads();
  for (int i=t;i<512;i+=256) d[i] *= inv;
  for (int i=t;i<511;i+=256) e[i] *= inv;
}

__global__ void k_tear(double* smalls, int sbase){
  int t = threadIdx.x;
  int sg = sbase + (t >> 5), k = (t & 31) + 1;
  if (k <= 31){
    double* d = smalls + (size_t)sg*512;
    double* e = smalls + 4096 + (size_t)sg*512;
    double ae = fabs(e[16*k - 1]);
    d[16*k - 1] -= ae;
    d[16*k]     -= ae;
  }
}

// 32 leaves of 16 per matrix; 8 leaves per block, threads 0..7 active
__global__ __launch_bounds__(64) void k_leaves(double* smalls, double* Zb, int sbase){
  __shared__ double LA[8][256];
  __shared__ double LQ[8][256];
  int t = threadIdx.x;
  if (t < 8){
    int bid = blockIdx.x;
    int s_local = bid >> 2;
    int sg = sbase + s_local;
    int leaf = (bid & 3)*8 + t;
    double* d = smalls + (size_t)sg*512;
    double* e = smalls + 4096 + (size_t)sg*512;
    double* Z = Zb + (size_t)s_local*MATSZ;
    int base = leaf*16;
    double* A = LA[t]; double* Q = LQ[t];
    for (int i=0;i<256;i++){ A[i]=0.0; Q[i]=0.0; }
    for (int i=0;i<16;i++){ A[i*17] = d[base+i]; Q[i*17] = 1.0; }
    for (int i=0;i<15;i++){ double ee = e[base+i]; A[i*16+i+1] = ee; A[(i+1)*16+i] = ee; }
    double nrm = 0.0;
    for (int i=0;i<256;i++) nrm += A[i]*A[i];
    double thr = nrm*1e-30 + 1e-300;
    for (int sweep=0; sweep<60; sweep++){
      double off = 0.0;
      for (int p=0;p<15;p++) for (int q=p+1;q<16;q++){
        double apq = A[p*16+q];
        off += 2.0*apq*apq;
        if (apq == 0.0) continue;
        double theta = 0.5*(A[q*17]-A[p*17])/apq;
        double tt;
        if (fabs(theta) > 1e18) tt = 0.5/theta;
        else tt = copysign(1.0, theta)/(fabs(theta)+sqrt(theta*theta+1.0));
        double cc = 1.0/sqrt(tt*tt+1.0), ss = tt*cc;
        for (int k=0;k<16;k++){
          double akp=A[k*16+p], akq=A[k*16+q];
          A[k*16+p] = cc*akp - ss*akq;
          A[k*16+q] = ss*akp + cc*akq;
        }
        for (int k=0;k<16;k++){
          double apk=A[p*16+k], aqk=A[q*16+k];
          A[p*16+k] = cc*apk - ss*aqk;
          A[q*16+k] = ss*apk + cc*aqk;
        }
        for (int k=0;k<16;k++){
          double qkp=Q[k*16+p], qkq=Q[k*16+q];
          Q[k*16+p] = cc*qkp - ss*qkq;
          Q[k*16+q] = ss*qkp + cc*qkq;
        }
      }
      if (off < thr) break;
    }
    for (int i=0;i<16;i++){
      int mi=i;
      for (int j=i+1;j<16;j++) if (A[j*17] < A[mi*17]) mi=j;
      if (mi!=i){
        double tmp=A[i*17]; A[i*17]=A[mi*17]; A[mi*17]=tmp;
        for (int k=0;k<16;k++){ double q1=Q[k*16+i]; Q[k*16+i]=Q[k*16+mi]; Q[k*16+mi]=q1; }
      }
    }
    for (int i=0;i<16;i++) d[base+i] = A[i*17];
    for (int r=0;r<16;r++)
      for (int c=0;c<16;c++)
        Z[(size_t)(base+r)*512 + base + c] = Q[r*16+c];
  }
}

// one block per merge: LAPACK slaed2 deflation + secular solve + Gu-Eisenstat
__global__ __launch_bounds__(256) void k_secular(double* smalls, const double* Zsrc_b,
                                                 double* Sm_b, int level, int sbase){
  const double EPS32 = 5.9604644775390625e-8;
  const double ISQ2  = 0.70710678118654752440;
  int s_local = blockIdx.x;
  int sg = sbase + s_local;
  int hh = 16 << level, n = hh << 1;
  int merge = blockIdx.y, start = merge*n;
  double* d = smalls + (size_t)sg*512;
  const double* e = smalls + 4096 + (size_t)sg*512;
  const double* Z = Zsrc_b + (size_t)s_local*MATSZ;
  double* Sm = Sm_b + (size_t)s_local*MATSZ;
  double* rotg = smalls + 12544 + (size_t)(sg*32+merge)*1024;
  __shared__ double ds[512], zl[512], dk[512], zk[512], tauk[512], zh[512], outlam[512];
  __shared__ double rc[256], rs[256];
  __shared__ double red[256];
  __shared__ double sv[2];
  __shared__ int perm[512], kidx[512], Ksk[512], didx[512], outid[512];
  __shared__ int rp[256], rq[256];
  __shared__ int counts[3];
  int t = threadIdx.x;
  if (t == 0){
    int i=0, j=hh, k=0;
    while (i < hh && j < n){
      if (d[start+i] <= d[start+j]) perm[k++]=i++; else perm[k++]=j++;
    }
    while (i < hh) perm[k++]=i++;
    while (j < n)  perm[k++]=j++;
  }
  __syncthreads();
  double eb = e[start+hh-1];
  double rho = 2.0*fabs(eb);
  double sgn = (eb < 0.0) ? -1.0 : 1.0;
  for (int i=t; i<n; i+=NT){
    int p = perm[i];
    ds[i] = d[start+p];
    double zr = (p < hh) ? Z[(size_t)(start+hh-1)*512 + start + p]
                         : sgn * Z[(size_t)(start+hh)*512 + start + p];
    zl[i] = zr * ISQ2;
  }
  __syncthreads();
  double m = 0.0;
  for (int i=t;i<n;i+=NT) m = fmax(m, fabs(zl[i]));
  red[t]=m; __syncthreads();
  for (int off=128; off; off>>=1){ if (t<off) red[t]=fmax(red[t],red[t+off]); __syncthreads(); }
  if (t==0) sv[0] = red[0];
  __syncthreads();
  m = 0.0;
  for (int i=t;i<n;i+=NT) m = fmax(m, fabs(ds[i]));
  red[t]=m; __syncthreads();
  for (int off=128; off; off>>=1){ if (t<off) red[t]=fmax(red[t],red[t+off]); __syncthreads(); }
  if (t==0) sv[1] = red[0];
  __syncthreads();
  double zmaxv = sv[0];
  double tol = 8.0*EPS32*fmax(sv[1], zmaxv);

  if (t == 0){
    int K=0, nd=0, nrot=0;
    if (rho*zmaxv <= tol){
      for (int j=0;j<n;j++) didx[nd++]=j;
    } else {
      int pj = -1;
      for (int j=0;j<n;j++){
        if (rho*fabs(zl[j]) <= tol){
          didx[nd++]=j;
        } else if (pj < 0){
          pj = j;
        } else {
          double s_ = zl[pj], c_ = zl[j];
          double tau2 = sqrt(c_*c_ + s_*s_);
          double tdf = ds[j] - ds[pj];
          double cc = c_/tau2, sr = -s_/tau2;
          if (fabs(tdf*cc*sr) <= tol){
            zl[j] = tau2; zl[pj] = 0.0;
            if (nrot < 256){
              rp[nrot]=perm[pj]; rq[nrot]=perm[j]; rc[nrot]=cc; rs[nrot]=sr; nrot++;
            }
            double tn = ds[pj]*cc*cc + ds[j]*sr*sr;
            ds[j]  = ds[pj]*sr*sr + ds[j]*cc*cc;
            ds[pj] = tn;
            didx[nd++] = pj;
            pj = j;
          } else {
            kidx[K++] = pj;
            pj = j;
          }
        }
      }
      if (pj >= 0) kidx[K++] = pj;
    }
    for (int a=1;a<nd;a++){
      int v = didx[a]; double dv = ds[v]; int b = a-1;
      while (b >= 0 && ds[didx[b]] > dv){ didx[b+1]=didx[b]; b--; }
      didx[b+1] = v;
    }
    counts[0]=K; counts[1]=nd; counts[2]=nrot;
    rotg[0] = (double)nrot;
    for (int i=0;i<nrot;i++){
      rotg[1+4*i]=(double)rp[i]; rotg[2+4*i]=(double)rq[i];
      rotg[3+4*i]=rc[i]; rotg[4+4*i]=rs[i];
    }
  }
  __syncthreads();
  int K = counts[0], nd = counts[1];

  for (int k=t; k<K; k+=NT){ dk[k]=ds[kidx[k]]; zk[k]=zl[kidx[k]]; }
  __syncthreads();

  for (int j2=t; j2<K; j2+=NT){
    int Kb; double lo, hi;
    if (j2 < K-1){
      double mid = 0.5*(dk[j2+1]-dk[j2]);
      double gg = 1.0;
      for (int i=0;i<K;i++){ double dif=(dk[i]-dk[j2])-mid; gg += rho*zk[i]*zk[i]/dif; }
      if (gg >= 0.0){ Kb=j2;   lo=0.0;  hi=mid; }
      else          { Kb=j2+1; lo=-mid; hi=0.0; }
    } else {
      double sz=0.0;
      for (int i=0;i<K;i++) sz += zk[i]*zk[i];
      Kb=K-1; lo=0.0; hi=rho*sz + 1e-300;
    }
    double dK = dk[Kb];
    for (int it=0; it<72; it++){
      double mid = 0.5*(lo+hi);
      if (mid==lo || mid==hi) break;
      double gg = 1.0;
      for (int i=0;i<K;i++){ double dif=(dk[i]-dK)-mid; gg += rho*zk[i]*zk[i]/dif; }
      if (gg < 0.0) lo=mid; else hi=mid;
    }
    Ksk[j2]=Kb; tauk[j2]=0.5*(lo+hi);
  }
  __syncthreads();
  for (int i=t; i<K; i+=NT){
    double P = (Ksk[i]==i) ? tauk[i] : (dk[Ksk[i]]-dk[i]) + tauk[i];
    for (int j=0;j<K;j++){
      if (j==i) continue;
      double num = (dk[Ksk[j]]-dk[i]) + tauk[j];
      double den = dk[j]-dk[i];
      P *= num/den;
    }
    zh[i] = copysign(sqrt(fabs(P/rho)), zk[i]);
  }
  __syncthreads();
  if (t == 0){
    int a=0, b=0;
    for (int j=0;j<n;j++){
      double la = (a<K)  ? (dk[Ksk[a]]+tauk[a]) : 1e300;
      double lb = (b<nd) ? ds[didx[b]]          : 1e300;
      if (la <= lb){ outid[j]=a;     outlam[j]=la; a++; }
      else         { outid[j]=512+b; outlam[j]=lb; b++; }
    }
  }
  __syncthreads();
  for (int j=t; j<n; j+=NT) d[start+j] = outlam[j];
  for (int j=t; j<n; j+=NT){
    double* col = Sm + (size_t)(start+j)*512;
    int id = outid[j];
    for (int i=0;i<n;i++) col[i]=0.0;
    if (id >= 512){
      col[perm[didx[id-512]]] = 1.0;
    } else {
      int k = id;
      double ss_ = 0.0;
      for (int i=0;i<K;i++){
        double dif = (dk[i]-dk[Ksk[k]]) - tauk[k];
        if (dif == 0.0) dif = 1e-300;
        double v = zh[i]/dif;
        col[perm[kidx[i]]] = v; ss_ += v*v;
      }
      double inv = 1.0/sqrt(ss_);
      for (int i=0;i<K;i++) col[perm[kidx[i]]] *= inv;
    }
  }
}

// apply recorded Givens rotations to S rows (reverse order)
__global__ __launch_bounds__(256) void k_rot(double* Sm_b, const double* smalls,
                                             int level, int sbase){
  int s_local = blockIdx.x, merge = blockIdx.y;
  int sg = sbase + s_local;
  int hh = 16 << level, n = hh << 1, start = merge*n;
  const double* rotg = smalls + 12544 + (size_t)(sg*32+merge)*1024;
  double* Sm = Sm_b + (size_t)s_local*MATSZ;
  int cnt = (int)rotg[0];
  for (int i=cnt-1; i>=0; i--){
    int p = (int)rotg[1+4*i], q = (int)rotg[2+4*i];
    double c = rotg[3+4*i], sr = rotg[4+4*i];
    for (int j=threadIdx.x; j<n; j+=256){
      double* col = Sm + (size_t)(start+j)*512;
      double a = col[p], b = col[q];
      col[p] = c*a - sr*b;
      col[q] = sr*a + c*b;
    }
    __syncthreads();
  }
}

// Zdst[merge square] = Zsrc[:,local-cols] * S
__global__ __launch_bounds__(256) void k_gemm64(const double* Zsrc_b, const double* Sm_b,
                                                double* Zdst_b, int level){
  int hh = 16 << level, n = hh << 1;
  int mpm = 512 / n;
  int bz = blockIdx.z;
  int s = bz / mpm, merge = bz % mpm;
  int start = merge*n;
  const double* Zs = Zsrc_b + (size_t)s*MATSZ;
  const double* Sm = Sm_b + (size_t)s*MATSZ;
  double* Zd = Zdst_b + (size_t)s*MATSZ;
  int row0 = start + blockIdx.y*32, col0 = start + blockIdx.x*32;
  int t = threadIdx.x;
  int tr = t >> 4, tc = t & 15;
  __shared__ double As[32][33];
  __shared__ double Bs[32][33];
  double a00=0,a01=0,a10=0,a11=0;
  for (int q0=0; q0<n; q0+=32){
    #pragma unroll
    for (int it=0; it<4; it++){
      int idx = t + it*256;
      int r = idx >> 5, q = idx & 31;
      As[r][q] = Zs[(size_t)(row0+r)*512 + start + q0 + q];
    }
    #pragma unroll
    for (int it=0; it<4; it++){
      int idx = t + it*256;
      int c = idx >> 5, q = idx & 31;
      Bs[q][c] = Sm[(size_t)(col0+c)*512 + q0 + q];
    }
    __syncthreads();
    #pragma unroll 8
    for (int q=0;q<32;q++){
      double ar0=As[tr][q], ar1=As[tr+16][q];
      double bc0=Bs[q][tc], bc1=Bs[q][tc+16];
      a00 = fma(ar0,bc0,a00); a01 = fma(ar0,bc1,a01);
      a10 = fma(ar1,bc0,a10); a11 = fma(ar1,bc1,a11);
    }
    __syncthreads();
  }
  Zd[(size_t)(row0+tr)*512 + col0+tc]       = a00;
  Zd[(size_t)(row0+tr)*512 + col0+tc+16]    = a01;
  Zd[(size_t)(row0+tr+16)*512 + col0+tc]    = a10;
  Zd[(size_t)(row0+tr+16)*512 + col0+tc+16] = a11;
}

// apply Q = H(1)...H(n-1) to Z from the left (reverse reflector order)
__global__ __launch_bounds__(256) void k_backq(double* Z2_b, const double* Vh_b,
                                               const double* smalls, int sbase){
  int s_local = blockIdx.x, cb = blockIdx.y;
  int sg = sbase + s_local;
  double* Z = Z2_b + (size_t)s_local*MATSZ;
  const double* V = Vh_b + (size_t)sg*MATSZ;
  const double* tu = smalls + 8192 + (size_t)sg*512;
  int cg = threadIdx.x >> 5, lane = threadIdx.x & 31;
  int c = cb*8 + cg;
  __shared__ double zc[8][512];
  for (int r=lane; r<512; r+=32) zc[cg][r] = Z[(size_t)r*512 + c];
  for (int i=509; i>=0; i--){
    double tv = tu[i];
    if (tv == 0.0) continue;
    double wp = 0.0;
    for (int r=i+1+lane; r<512; r+=32) wp += V[(size_t)i*512 + r]*zc[cg][r];
    #pragma unroll
    for (int off=16; off; off>>=1) wp += __shfl_down(wp, off, 32);
    double w = __shfl(wp, 0, 32);
    double tw = tv*w;
    for (int r=i+1+lane; r<512; r+=32) zc[cg][r] -= tw*V[(size_t)i*512 + r];
  }
  for (int r=lane; r<512; r+=32) Z[(size_t)r*512 + c] = zc[cg][r];
}

__global__ void k_finalize(const double* Z2_b, const double* smalls,
                           float* Vt_pass, float* eig, int pass, int sbase){
  int s_local = blockIdx.x;
  int sg = sbase + s_local;
  const double* Z = Z2_b + (size_t)s_local*MATSZ;
  double org = smalls[12288+sg];
  int idx = blockIdx.y*256 + threadIdx.x;
  int r = idx >> 9, c = idx & 511;
  Vt_pass[(size_t)s_local*MATSZ + (size_t)c*512 + r] = (float)Z[(size_t)r*512 + c];
  if (idx < 512)
    eig[(size_t)(pass*4+s_local)*512 + idx] = (float)(smalls[(size_t)sg*512 + idx]*org);
}

// --------------------------- diffusion (f32) --------------------------------
struct KArgs {
  const float* Vt;
  const float* Vt2;
  float *xspec, *hbuf, *x, *E;
  const float *W1s, *W1t, *W2s, *W2t;
  const float *b2s, *b2t, *wts, *wtt, *b1s, *b1t, *wes, *wet;
  const float *cond, *Wcs, *Wct;
  const float *eig;
  const float *rec, *recW, *recb;
  float* out;
  float t, a, bc;
  unsigned nk0, nk1, nk2, nk3;
  int mode;
};

// vectorized GEMM: per-element accumulation order (k0 asc, kk asc, single
// accumulator) identical to prior rounds -> bit-identical outputs.
__global__ __launch_bounds__(256) void k_gemm32(KArgs P){
  int t = threadIdx.x;
  int tr4 = (t >> 4) << 2, tc4 = (t & 15) << 2;
  int bz = blockIdx.z;
  int m0 = blockIdx.y << 6, n0 = blockIdx.x << 6;
  const float *A, *B; float *C;
  int lda, K, chain = 0;
  if (P.mode == 0){
    A = (bz < 4) ? (P.Vt + (size_t)bz*MATSZ) : (P.Vt2 + (size_t)(bz-4)*MATSZ);
    lda = 512; K = 512;
    B = P.x + (size_t)bz*SZF; C = P.xspec + (size_t)bz*SZF;
  } else if (P.mode == 1){
    chain = bz >> 2;
    A = P.xspec + (size_t)bz*SZF; lda = 256; K = 256;
    B = chain ? P.W1t : P.W1s; C = P.hbuf + (size_t)bz*SZF;
  } else if (P.mode == 2){
    chain = bz >> 2;
    A = P.hbuf + (size_t)bz*SZF; lda = 256; K = 256;
    B = chain ? P.W2t : P.W2s; C = P.x + (size_t)bz*SZF;
  } else if (P.mode == 3){
    chain = bz;
    A = P.cond; lda = 256; K = 256;
    B = chain ? P.Wct : P.Wcs; C = P.E + (size_t)chain*4*SZF;
  } else {
    A = P.rec; lda = 256; K = 256;
    B = P.recW; C = P.out;
  }
  __shared__ float As[16][68];
  __shared__ float Bs[16][68];
  float acc[4][4] = {{0}};
  for (int k0=0; k0<K; k0+=16){
    {
      int r = t >> 2, kk4 = (t & 3) << 2;
      const float4 av = *(const float4*)&A[(size_t)(m0 + r)*lda + k0 + kk4];
      As[kk4+0][r]=av.x; As[kk4+1][r]=av.y; As[kk4+2][r]=av.z; As[kk4+3][r]=av.w;
    }
    {
      int kk = t >> 4, c4 = (t & 15) << 2;
      *(float4*)&Bs[kk][c4] = *(const float4*)&B[(size_t)(k0 + kk)*256 + n0 + c4];
    }
    __syncthreads();
    #pragma unroll
    for (int kk=0; kk<16; kk++){
      const float4 a4 = *(const float4*)&As[kk][tr4];
      const float4 b4 = *(const float4*)&Bs[kk][tc4];
      const float ar[4] = {a4.x, a4.y, a4.z, a4.w};
      const float bv[4] = {b4.x, b4.y, b4.z, b4.w};
      #pragma unroll
      for (int q=0;q<4;q++)
        #pragma unroll
        for (int p=0;p<4;p++)
          acc[q][p] = fmaf(ar[q], bv[p], acc[q][p]);
    }
    __syncthreads();
  }
  #pragma unroll
  for (int q=0;q<4;q++){
    int r = m0 + tr4 + q;
    size_t rowoff = (size_t)r*256 + n0 + tc4;
    float4 cv;
    if (P.mode == 2) cv = *(const float4*)&C[rowoff];
    float res[4];
    #pragma unroll
    for (int p=0;p<4;p++){
      int c = n0 + tc4 + p;
      size_t oi = (size_t)r*256 + c;
      float v = acc[q][p];
      if (P.mode == 1){
        v += P.E[(size_t)bz*SZF + oi] + P.t * ((chain ? P.wtt : P.wts)[c]);
        float sg = 1.0f/(1.0f + expf(-v));
        v = v * sg;
      } else if (P.mode == 2){
        float bias = (chain ? P.b2t : P.b2s)[c];
        unsigned j = ((unsigned)(bz & 3))*131072u + (unsigned)oi;
        unsigned kk0 = chain ? P.nk2 : P.nk0;
        unsigned kk1 = chain ? P.nk3 : P.nk1;
        unsigned y0, y1;
        tf2x32(kk0, kk1, 0u, j, &y0, &y1);
        float nz = bits_to_normal(y0 ^ y1);
        float cx = ((const float*)&cv)[p];
        v = cx + P.a*(v + bias) + P.bc*nz;
      } else if (P.mode == 3){
        int bb = r >> 9, s2 = r & 511;
        v += (chain ? P.b1t : P.b1s)[c]
           + P.eig[(size_t)(chain*4 + bb)*512 + s2] * ((chain ? P.wet : P.wes)[c]);
      } else if (P.mode == 4){
        v += P.recb[c];
      }
      res[p] = v;
    }
    *(float4*)&C[rowoff] = make_float4(res[0], res[1], res[2], res[3]);
  }
}

__global__ void k_cond(float* cond, const float* a, const float* v){
  size_t i = (size_t)blockIdx.x*256 + threadIdx.x;
  cond[i] = 0.5f*(a[i] + v[i]);
}

__global__ void k_xinit(float* x, const float* xT){
  size_t i = (size_t)blockIdx.x*256 + threadIdx.x;
  size_t b = i >> 17, off = i & 131071;
  x[i] = xT[((b & 3) << 17) + off];
}

__global__ void k_rec(float* rec, const float* x){
  size_t i = (size_t)blockIdx.x*256 + threadIdx.x;
  rec[i] = 0.5f*(x[i] + x[i + 524288]);
}

__global__ void k_copy(float* out, const float* a, const float* v){
  size_t i = (size_t)blockIdx.x*256 + threadIdx.x;
  out[524288 + i] = (i < 524288) ? a[i] : v[i - 524288];
}

// ------------------------------- host --------------------------------------
extern "C" void kernel_launch(void* const* d_in, const int* in_sizes, int n_in,
                              void* d_out, int out_size, void* d_ws, size_t ws_size,
                              hipStream_t stream){
  const float* f_audio   = (const float*)d_in[1];
  const float* f_visual  = (const float*)d_in[2];
  const float* g_speaker = (const float*)d_in[3];
  const float* g_temporal= (const float*)d_in[4];
  const float* x_T       = (const float*)d_in[6];
  const float* tsW1=(const float*)d_in[7],  *tswe=(const float*)d_in[8],
             * tswt=(const float*)d_in[9],  *tsb1=(const float*)d_in[10],
             * tsWc=(const float*)d_in[11], *tsW2=(const float*)d_in[12],
             * tsb2=(const float*)d_in[13];
  const float* ttW1=(const float*)d_in[14], *ttwe=(const float*)d_in[15],
             * ttwt=(const float*)d_in[16], *ttb1=(const float*)d_in[17],
             * ttWc=(const float*)d_in[18], *ttW2=(const float*)d_in[19],
             * ttb2=(const float*)d_in[20];
  const float* recW=(const float*)d_in[21], *recb=(const float*)d_in[22];
  float* out = (float*)d_out;

  const size_t MB = 1ull << 20;
  if (ws_size < 43*MB) return;

  char* ws = (char*)d_ws;
  double* Vh     = (double*)(ws + 0);
  double* Atail  = (double*)(ws + 16*MB);    // 8 full-stride slots (sparse use)
  double* A64    = (double*)(ws + 16*MB);    // D&C overlay (after tail)
  double* Zb     = (double*)(ws + 24*MB);
  double* Sm     = (double*)(ws + 32*MB);
  double* smalls = (double*)(ws + 40*MB);
  unsigned* slots = (unsigned*)(smalls + 295168);
  float* Vt32_s  = (float*)(ws + 0);
  float* Vt32_t  = (float*)(ws + 8*MB);
  float* eig32   = (float*)(ws + 42*MB + 512*1024);
  float* cond  = (float*)(ws + 16*MB);
  float* E     = (float*)(ws + 18*MB);
  float* xall  = (float*)(ws + 22*MB);
  float* xspec = (float*)(ws + 26*MB);
  float* hbuf  = (float*)(ws + 30*MB);

  // ---- jax.random key schedule (host, exact threefry, PARTITIONABLE) ----
  unsigned f0, f1;
  tf2x32(0u, 42u, 0u, 0u, &f0, &f1);
  unsigned s0,s1,t0,t1;
  tf2x32(f0, f1, 0u, 0u, &s0, &s1);
  tf2x32(f0, f1, 0u, 1u, &t0, &t1);
  unsigned skeys[100][2], tkeys[100][2];
  for (int k=0; k<100; k++){
    tf2x32(s0, s1, 0u, (unsigned)k, &skeys[k][0], &skeys[k][1]);
    tf2x32(t0, t1, 0u, (unsigned)k, &tkeys[k][0], &tkeys[k][1]);
  }

  hipMemsetAsync(slots, 0, 16384, stream);

  // ---- eigh: persistent head (cols 0..383) + single-block tail ----
  k_sytd2_lds<<<8*NB, 256, 0, stream>>>(g_speaker, g_temporal, Vh, smalls, slots, Atail);
  k_sy_tail<<<8, 256, 0, stream>>>(Atail, Vh, smalls);

  for (int pass=0; pass<2; pass++){
    int sbase = 4*pass;
    k_scale<<<4, 256, 0, stream>>>(smalls, sbase);
    hipMemsetAsync(Zb, 0, 8*MB, stream);
    hipMemsetAsync(A64, 0, 8*MB, stream);
    k_tear<<<1, 128, 0, stream>>>(smalls, sbase);
    k_leaves<<<16, 64, 0, stream>>>(smalls, Zb, sbase);
    for (int level=0; level<5; level++){
      int n = 32 << level, mpm = 512/n;
      double* src = (level & 1) ? A64 : Zb;
      double* dst = (level & 1) ? Zb  : A64;
      k_secular<<<dim3(4, mpm), 256, 0, stream>>>(smalls, src, Sm, level, sbase);
      k_rot<<<dim3(4, mpm), 256, 0, stream>>>(Sm, smalls, level, sbase);
      k_gemm64<<<dim3(n/32, n/32, 4*mpm), 256, 0, stream>>>(src, Sm, dst, level);
    }
    k_backq<<<dim3(4, 64), 256, 0, stream>>>(A64, Vh, smalls, sbase);
    k_finalize<<<dim3(4, 1024), 256, 0, stream>>>(A64, smalls,
                                                  pass ? Vt32_t : Vt32_s,
                                                  eig32, pass, sbase);
  }

  // ---- diffusion ----
  k_cond<<<2048, 256, 0, stream>>>(cond, f_audio, f_visual);
  k_xinit<<<4096, 256, 0, stream>>>(xall, x_T);

  KArgs P;
  P.Vt = Vt32_s; P.Vt2 = Vt32_t;
  P.xspec = xspec; P.hbuf = hbuf; P.x = xall; P.E = E;
  P.W1s = tsW1; P.W1t = ttW1; P.W2s = tsW2; P.W2t = ttW2;
  P.b2s = tsb2; P.b2t = ttb2; P.wts = tswt; P.wtt = ttwt;
  P.b1s = tsb1; P.b1t = ttb1; P.wes = tswe; P.wet = ttwe;
  P.cond = cond; P.Wcs = tsWc; P.Wct = ttWc;
  P.eig = eig32; P.rec = xspec; P.recW = recW; P.recb = recb; P.out = out;
  P.t = 0.f; P.a = 0.f; P.bc = 0.f;
  P.nk0 = 0; P.nk1 = 0; P.nk2 = 0; P.nk3 = 0;

  P.mode = 3;
  k_gemm32<<<dim3(4, 32, 2), 256, 0, stream>>>(P);

  for (int k=0; k<100; k++){
    float tf = (float)(1.0 - (double)k/99.0);
    float av = (float)(pow(25.0, 2.0*(double)tf) * 0.01);
    float bcv = (float)(pow(25.0, (double)tf) * 0.1);
    P.nk0 = skeys[k][0]; P.nk1 = skeys[k][1];
    P.nk2 = tkeys[k][0]; P.nk3 = tkeys[k][1];
    P.mode = 0;
    k_gemm32<<<dim3(4, 8, 8), 256, 0, stream>>>(P);
    P.mode = 1; P.t = tf;
    k_gemm32<<<dim3(4, 8, 8), 256, 0, stream>>>(P);
    P.mode = 2; P.a = av; P.bc = bcv;
    k_gemm32<<<dim3(4, 8, 8), 256, 0, stream>>>(P);
  }

  k_rec<<<2048, 256, 0, stream>>>(xspec, xall);
  P.mode = 4; P.rec = xspec;
  k_gemm32<<<dim3(4, 32, 1), 256, 0, stream>>>(P);
  k_copy<<<4096, 256, 0, stream>>>(out, f_audio, f_visual);
}